// Round 5
// baseline (193.441 us; speedup 1.0000x reference)
//
#include <hip/hip_runtime.h>
#include <cstdint>

// Problem constants (fixed by the reference: B=64,S=512,IN=OUT=256,R=40,NB=3,E=262144)
#define N_NODES 32768
#define IN_F    256
#define OUT_F   256
#define NBASES  3
#define N_EDGES 262144
#define K_DIM   (NBASES * IN_F)    // 768: GEMM reduction dim (b*256 + i)

typedef __attribute__((ext_vector_type(8))) short bf16x8;
typedef __attribute__((ext_vector_type(4))) float f32x4;

__device__ __forceinline__ unsigned short f2bf(float x) {
    union { float f; unsigned int u; } c; c.f = x;
    unsigned int u = c.u;
    u = (u + 0x7FFFu + ((u >> 16) & 1u)) >> 16;   // round-to-nearest-even
    return (unsigned short)u;
}
__device__ __forceinline__ float bf2f(unsigned short h) {
    union { unsigned int u; float f; } c; c.u = ((unsigned int)h) << 16;
    return c.f;
}

__device__ __forceinline__ void async_copy16(const void* g, void* l) {
    __builtin_amdgcn_global_load_lds(
        (const __attribute__((address_space(1))) unsigned int*)g,
        (__attribute__((address_space(3))) unsigned int*)l, 16, 0, 0);
}

// ---------------------------------------------------------------------------
// Prep (fused): blocks [0,8192) convert text f32 -> hb bf16; blocks
// [8192,8384) transpose bases -> Wt bf16; blocks [8384,8512) zero counts.
// ---------------------------------------------------------------------------
__global__ __launch_bounds__(256) void prep_kernel(
    const float* __restrict__ text,     // [N_NODES, 256] f32
    const float* __restrict__ bases,    // [768, 256] f32
    unsigned short* __restrict__ hb,    // [N_NODES, 256] bf16 (may be null)
    unsigned short* __restrict__ Wt,    // [256, 768] bf16
    int* __restrict__ counts)           // [N_NODES] -> zeroed
{
    const int tid = threadIdx.x;
    if (blockIdx.x < 8192) {
        if (!hb) return;
        int i = blockIdx.x * 256 + tid;            // float4 index
        float4 v = reinterpret_cast<const float4*>(text)[i];
        ushort4 o;
        o.x = f2bf(v.x); o.y = f2bf(v.y); o.z = f2bf(v.z); o.w = f2bf(v.w);
        reinterpret_cast<ushort4*>(hb)[i] = o;
    } else if (blockIdx.x < 8384) {
        int tb = blockIdx.x - 8192;                // [0,192)
        int kb = tb % 24, ob = tb / 24;            // 32-wide tiles
        __shared__ float tile[32][33];
        int c = tid & 31, r8 = tid >> 5;
        #pragma unroll
        for (int i = 0; i < 4; ++i) {
            int r = r8 + 8 * i;
            tile[r][c] = bases[(size_t)(kb * 32 + r) * OUT_F + ob * 32 + c];
        }
        __syncthreads();
        #pragma unroll
        for (int i = 0; i < 4; ++i) {
            int r = r8 + 8 * i;                    // output row within o-tile
            Wt[(size_t)(ob * 32 + r) * K_DIM + kb * 32 + c] = f2bf(tile[c][r]);
        }
    } else {
        int i = (blockIdx.x - 8384) * 256 + tid;   // [0, 32768)
        counts[i] = 0;
    }
}

// ---------------------------------------------------------------------------
// Counting sort of edges by dst: histogram -> scan -> scatter(packed)
// ---------------------------------------------------------------------------
__global__ __launch_bounds__(256) void hist_kernel(
    const int* __restrict__ dst, int* __restrict__ counts)
{
    int e4 = blockIdx.x * 256 + threadIdx.x;
    int4 d = reinterpret_cast<const int4*>(dst)[e4];
    atomicAdd(&counts[d.x], 1);
    atomicAdd(&counts[d.y], 1);
    atomicAdd(&counts[d.z], 1);
    atomicAdd(&counts[d.w], 1);
}

// Single block, 1024 threads, 32 counters each. Converts counts -> cursor
// in place and writes the exclusive-scan offsets.
__global__ __launch_bounds__(1024) void scan_kernel(
    int* __restrict__ counts,        // in: histogram; out: cursor (in place)
    int* __restrict__ offsets)       // [N_NODES+1]
{
    __shared__ int wsum[16];
    const int tid = threadIdx.x;
    const int wave = tid >> 6, lane = tid & 63;
    const int base = tid * 32;
    int local[32];
    int sum = 0;
    #pragma unroll
    for (int k8 = 0; k8 < 8; ++k8) {
        int4 v = reinterpret_cast<const int4*>(counts + base)[k8];
        local[k8 * 4 + 0] = v.x; local[k8 * 4 + 1] = v.y;
        local[k8 * 4 + 2] = v.z; local[k8 * 4 + 3] = v.w;
        sum += v.x + v.y + v.z + v.w;
    }
    int inc = sum;                            // wave-inclusive scan of sums
    #pragma unroll
    for (int off = 1; off < 64; off <<= 1) {
        int v = __shfl_up(inc, off);
        if (lane >= off) inc += v;
    }
    if (lane == 63) wsum[wave] = inc;
    __syncthreads();
    if (wave == 0 && lane < 16) {             // scan the 16 wave totals
        int v = wsum[lane];
        #pragma unroll
        for (int off = 1; off < 16; off <<= 1) {
            int u = __shfl_up(v, off);
            if (lane >= off) v += u;
        }
        wsum[lane] = v;
    }
    __syncthreads();
    int run = inc - sum + (wave ? wsum[wave - 1] : 0);   // exclusive prefix
    #pragma unroll
    for (int k = 0; k < 32; ++k) {
        offsets[base + k] = run;
        counts[base + k] = run;               // cursor
        run += local[k];
    }
    if (tid == 1023) offsets[N_NODES] = run;  // == N_EDGES
}

__global__ __launch_bounds__(256) void scatter_kernel(
    const int* __restrict__ dst, const int* __restrict__ src,
    const int* __restrict__ rel, int* __restrict__ cursor,
    int* __restrict__ packed)                 // sorted (rel<<16)|src
{
    int e4 = blockIdx.x * 256 + threadIdx.x;
    int4 d = reinterpret_cast<const int4*>(dst)[e4];
    int4 s = reinterpret_cast<const int4*>(src)[e4];
    int4 r = reinterpret_cast<const int4*>(rel)[e4];
    int p0 = atomicAdd(&cursor[d.x], 1);
    packed[p0] = (r.x << 16) | s.x;
    int p1 = atomicAdd(&cursor[d.y], 1);
    packed[p1] = (r.y << 16) | s.y;
    int p2 = atomicAdd(&cursor[d.z], 1);
    packed[p2] = (r.z << 16) | s.z;
    int p3 = atomicAdd(&cursor[d.w], 1);
    packed[p3] = (r.w << 16) | s.w;
}

// ---------------------------------------------------------------------------
// Aggregation in INPUT space: z[n, b, i] = sum_{e: dst=n} comp[rel_e,b]*h[src_e,i]
// One wave per dst node; lane owns 4 input features; 4-deep unrolled inner
// loop (mask-folded coefficients -> no tail branches, 4 gathers in flight).
// ---------------------------------------------------------------------------
__global__ __launch_bounds__(256) void agg_bf16_kernel(
    const unsigned short* __restrict__ hb,    // [N_NODES, 256] bf16
    const int* __restrict__ packed,           // sorted by dst
    const int* __restrict__ offsets,          // [N_NODES+1]
    const float* __restrict__ comp,           // [40, 3]
    unsigned short* __restrict__ z)           // [N_NODES, 768] bf16
{
    __shared__ float compS[128];
    if (threadIdx.x < 120) compS[threadIdx.x] = comp[threadIdx.x];
    __syncthreads();

    const int node = blockIdx.x * 4 + (threadIdx.x >> 6);
    const int lane = threadIdx.x & 63;
    const int start = offsets[node];
    const int end   = offsets[node + 1];

    float a0[4] = {}, a1[4] = {}, a2[4] = {};

    for (int cb = start; cb < end; cb += 64) {
        int idx = cb + lane;
        int pv = (idx < end) ? packed[idx] : 0;
        int cnt = min(64, end - cb);
        for (int j = 0; j < cnt; j += 4) {
            float c0[4], c1[4], c2[4];
            ushort4 u[4];
            #pragma unroll
            for (int q = 0; q < 4; ++q) {
                int p = __shfl(pv, j + q);
                int s = p & 0xFFFF, r = p >> 16;
                float m = (j + q < cnt) ? 1.f : 0.f;
                c0[q] = m * compS[r * 3 + 0];
                c1[q] = m * compS[r * 3 + 1];
                c2[q] = m * compS[r * 3 + 2];
                u[q] = *reinterpret_cast<const ushort4*>(
                    hb + (size_t)s * IN_F + lane * 4);
            }
            #pragma unroll
            for (int q = 0; q < 4; ++q) {
                float v[4] = { bf2f(u[q].x), bf2f(u[q].y),
                               bf2f(u[q].z), bf2f(u[q].w) };
                #pragma unroll
                for (int k = 0; k < 4; ++k) {
                    a0[k] += c0[q] * v[k];
                    a1[k] += c1[q] * v[k];
                    a2[k] += c2[q] * v[k];
                }
            }
        }
    }

    unsigned short* zp = z + (size_t)node * K_DIM + lane * 4;
    ushort4 o;
    o.x = f2bf(a0[0]); o.y = f2bf(a0[1]); o.z = f2bf(a0[2]); o.w = f2bf(a0[3]);
    *reinterpret_cast<ushort4*>(zp) = o;
    o.x = f2bf(a1[0]); o.y = f2bf(a1[1]); o.z = f2bf(a1[2]); o.w = f2bf(a1[3]);
    *reinterpret_cast<ushort4*>(zp + 256) = o;
    o.x = f2bf(a2[0]); o.y = f2bf(a2[1]); o.z = f2bf(a2[2]); o.w = f2bf(a2[3]);
    *reinterpret_cast<ushort4*>(zp + 512) = o;
}

// f32 fallback (used only if ws_size can't fit hb)
__global__ __launch_bounds__(256) void agg_f32_kernel(
    const float* __restrict__ h,
    const int* __restrict__ packed,
    const int* __restrict__ offsets,
    const float* __restrict__ comp,
    unsigned short* __restrict__ z)
{
    __shared__ float compS[128];
    if (threadIdx.x < 120) compS[threadIdx.x] = comp[threadIdx.x];
    __syncthreads();
    const int node = blockIdx.x * 4 + (threadIdx.x >> 6);
    const int lane = threadIdx.x & 63;
    const int start = offsets[node];
    const int end   = offsets[node + 1];
    float a0[4] = {}, a1[4] = {}, a2[4] = {};
    for (int cb = start; cb < end; cb += 64) {
        int idx = cb + lane;
        int pv = (idx < end) ? packed[idx] : 0;
        int cnt = min(64, end - cb);
        for (int j = 0; j < cnt; ++j) {
            int p = __shfl(pv, j);
            int s = p & 0xFFFF, r = p >> 16;
            float c0 = compS[r*3], c1 = compS[r*3+1], c2 = compS[r*3+2];
            float4 v = *reinterpret_cast<const float4*>(
                h + (size_t)s * IN_F + lane * 4);
            a0[0] += c0*v.x; a0[1] += c0*v.y; a0[2] += c0*v.z; a0[3] += c0*v.w;
            a1[0] += c1*v.x; a1[1] += c1*v.y; a1[2] += c1*v.z; a1[3] += c1*v.w;
            a2[0] += c2*v.x; a2[1] += c2*v.y; a2[2] += c2*v.z; a2[3] += c2*v.w;
        }
    }
    unsigned short* zp = z + (size_t)node * K_DIM + lane * 4;
    ushort4 o;
    o.x = f2bf(a0[0]); o.y = f2bf(a0[1]); o.z = f2bf(a0[2]); o.w = f2bf(a0[3]);
    *reinterpret_cast<ushort4*>(zp) = o;
    o.x = f2bf(a1[0]); o.y = f2bf(a1[1]); o.z = f2bf(a1[2]); o.w = f2bf(a1[3]);
    *reinterpret_cast<ushort4*>(zp + 256) = o;
    o.x = f2bf(a2[0]); o.y = f2bf(a2[1]); o.z = f2bf(a2[2]); o.w = f2bf(a2[3]);
    *reinterpret_cast<ushort4*>(zp + 512) = o;
}

// ---------------------------------------------------------------------------
// GEMM: out[m, o] = relu( sum_k z[m,k] * Wt[o,k] + bias[o] )
// M=32768, N=256, K=768. 64x128 tile -> grid (512,2) = 1024 blocks (4+/CU),
// 4 waves (2x2, each 32x64), MFMA 16x16x32, double-buffered global_load_lds
// into XOR-swizzled [row][k-octet] LDS (2-way max aliasing = free).
// ---------------------------------------------------------------------------
__global__ __launch_bounds__(256) void gemm_kernel(
    const unsigned short* __restrict__ A,   // z  [32768, 768] bf16
    const unsigned short* __restrict__ Bt,  // Wt [256, 768] bf16
    const float* __restrict__ bias,         // [256]
    float* __restrict__ out)                // [32768, 256] f32
{
    __shared__ __align__(16) unsigned short As[2][64 * 32];    // 4 KB each
    __shared__ __align__(16) unsigned short Bs[2][128 * 32];   // 8 KB each

    const int tid  = threadIdx.x;
    const int wave = tid >> 6, lane = tid & 63;
    const int quad = lane >> 4, l16 = lane & 15;
    const int wm = (wave & 1) * 32, wn = (wave >> 1) * 64;
    const int m0 = blockIdx.x * 64, n0 = blockIdx.y * 128;

    f32x4 acc[2][4] = {};

    // Staging maps: slot p <- logical (row = p>>2, oct = (p&3)^((row>>1)&3)).
    // A: 256 slots (1 per thread); B: 512 slots (2 per thread).
    const int pa   = wave * 64 + lane;
    const int rowa = pa >> 2;
    const int octa = (pa & 3) ^ ((rowa >> 1) & 3);
    const unsigned short* ga = A + (size_t)(m0 + rowa) * K_DIM + octa * 8;
    const int la_off = (wave * 64) * 8;               // wave-uniform LDS base

    const unsigned short* gb[2];
    int lb_off[2];
    #pragma unroll
    for (int c = 0; c < 2; ++c) {
        int p   = c * 256 + wave * 64 + lane;
        int row = p >> 2;
        int oct = (p & 3) ^ ((row >> 1) & 3);
        gb[c] = Bt + (size_t)(n0 + row) * K_DIM + oct * 8;
        lb_off[c] = (c * 256 + wave * 64) * 8;
    }

    // Prologue: stage k0 = 0 into buffer 0.
    async_copy16(ga, &As[0][la_off]);
    async_copy16(gb[0], &Bs[0][lb_off[0]]);
    async_copy16(gb[1], &Bs[0][lb_off[1]]);

    int cur = 0;
    for (int step = 0; step < K_DIM / 32; ++step) {
        __syncthreads();   // waves drained own vmcnt here -> buf[cur] ready
        int k1 = (step + 1) * 32;
        if (k1 < K_DIM) {  // prefetch next slab; overlaps the MFMA phase below
            async_copy16(ga + k1, &As[cur ^ 1][la_off]);
            async_copy16(gb[0] + k1, &Bs[cur ^ 1][lb_off[0]]);
            async_copy16(gb[1] + k1, &Bs[cur ^ 1][lb_off[1]]);
        }

        bf16x8 af[2], bfr[4];
        #pragma unroll
        for (int i = 0; i < 2; ++i) {
            int row = wm + i * 16 + l16;
            int oph = quad ^ ((row >> 1) & 3);
            af[i] = *reinterpret_cast<const bf16x8*>(&As[cur][(row * 4 + oph) * 8]);
        }
        #pragma unroll
        for (int j = 0; j < 4; ++j) {
            int nn   = wn + j * 16 + l16;
            int oph2 = quad ^ ((nn >> 1) & 3);
            bfr[j] = *reinterpret_cast<const bf16x8*>(&Bs[cur][(nn * 4 + oph2) * 8]);
        }
        #pragma unroll
        for (int i = 0; i < 2; ++i)
            #pragma unroll
            for (int j = 0; j < 4; ++j)
                acc[i][j] = __builtin_amdgcn_mfma_f32_16x16x32_bf16(
                    af[i], bfr[j], acc[i][j], 0, 0, 0);
        cur ^= 1;
    }

    // Epilogue: C/D layout col = l16, row = quad*4 + r. Fused bias + ReLU.
    #pragma unroll
    for (int j = 0; j < 4; ++j) {
        int col = n0 + wn + j * 16 + l16;
        float bv = bias[col];
        #pragma unroll
        for (int i = 0; i < 2; ++i) {
            int row_base = m0 + wm + i * 16 + quad * 4;
            #pragma unroll
            for (int r = 0; r < 4; ++r)
                out[(size_t)(row_base + r) * OUT_F + col] =
                    fmaxf(acc[i][j][r] + bv, 0.f);
        }
    }
}

extern "C" void kernel_launch(void* const* d_in, const int* in_sizes, int n_in,
                              void* d_out, int out_size, void* d_ws, size_t ws_size,
                              hipStream_t stream) {
    const float* text  = (const float*)d_in[0];   // [64,512,256] f32
    const int*   src   = (const int*)d_in[1];     // [E]
    const int*   dst   = (const int*)d_in[2];     // [E]
    const int*   rel   = (const int*)d_in[3];     // [E]
    const float* bases = (const float*)d_in[4];   // [3,256,256] f32 = [768,256]
    const float* comp  = (const float*)d_in[5];   // [40,3] f32
    const float* bias  = (const float*)d_in[6];   // [256] f32
    float* out = (float*)d_out;

    // Workspace layout (all chunks 16B-aligned):
    //   z       : N*768*2      = 50,331,648 B
    //   packed  : E*4          =  1,048,576 B
    //   offsets : (N+4)*4      =    131,088 B
    //   counts  : N*4          =    131,072 B
    //   Wt      : 256*768*2    =    393,216 B   -> 52,035,600 B required
    //   hb      : N*256*2      = 16,777,216 B   -> 68,812,816 B optional
    char* p = (char*)d_ws;
    unsigned short* z = (unsigned short*)p;       p += (size_t)N_NODES * K_DIM * 2;
    int* packed  = (int*)p;                       p += (size_t)N_EDGES * 4;
    int* offsets = (int*)p;                       p += (size_t)(N_NODES + 4) * 4;
    int* counts  = (int*)p;                       p += (size_t)N_NODES * 4;
    unsigned short* Wt = (unsigned short*)p;      p += (size_t)OUT_F * K_DIM * 2;
    bool use_bf16_h = (ws_size >= (size_t)(p - (char*)d_ws) + (size_t)N_NODES * IN_F * 2);
    unsigned short* hb = use_bf16_h ? (unsigned short*)p : nullptr;

    prep_kernel<<<8512, 256, 0, stream>>>(text, bases, hb, Wt, counts);
    hist_kernel<<<N_EDGES / 1024, 256, 0, stream>>>(dst, counts);
    scan_kernel<<<1, 1024, 0, stream>>>(counts, offsets);
    scatter_kernel<<<N_EDGES / 1024, 256, 0, stream>>>(dst, src, rel, counts, packed);
    if (use_bf16_h)
        agg_bf16_kernel<<<N_NODES / 4, 256, 0, stream>>>(hb, packed, offsets, comp, z);
    else
        agg_f32_kernel<<<N_NODES / 4, 256, 0, stream>>>(text, packed, offsets, comp, z);
    gemm_kernel<<<dim3(N_NODES / 64, OUT_F / 128), 256, 0, stream>>>(
        z, Wt, bias, out);
}